// Round 10
// baseline (177.814 us; speedup 1.0000x reference)
//
#include <hip/hip_runtime.h>
#include <math.h>

// Problem constants: N=8, S=8192, C=1, K=1024, V=64
#define NS   65536
#define KK   1024
#define VV   64
#define SPB  64               // samples per block (4 m-tiles of 16)
#define NB   (NS / SPB)       // 1024 blocks
#define NW   8                // waves per block (512 threads)
#define TPW  2                // code tiles per wave per pass (32 codes)
#define NPASS 4               // 8 waves x 2 tiles x 4 passes = 64 tiles = 1024 codes
#define NMT  (SPB / 16)       // 4 sample-tiles per block

// Output layout (flat, return order):
#define OUT0_OFF 0            // (8,8192,1,64) = 4,194,304
#define OUT1_OFF 4194304
#define OUT2_OFF 4259840
#define ENT_OFF  4325376      // entropy scalar

// ws layout: [0,4K) hist u32; [4K,8K) cinit f32; [8K,136K) frag-linear bf16 codebook;
//            [1M, 1M+2MB) probe sink scratch (diagnostic only)

typedef __attribute__((ext_vector_type(8))) short bf16x8;
typedef __attribute__((ext_vector_type(4))) float f32x4;

__device__ __forceinline__ short f2bf(float f) {
    unsigned u = __float_as_uint(f);
    u = (u + 0x7fffu + ((u >> 16) & 1u)) >> 16;   // RNE
    return (short)u;
}

// prep (wide): 8192 threads, one (code, granule) each. FRAG-LINEAR bf16 codebook.
__global__ void vq_prep(const float* __restrict__ emb, unsigned int* __restrict__ hist,
                        float* __restrict__ cinit, short* __restrict__ cb) {
    const int t = blockIdx.x * blockDim.x + threadIdx.x;   // 0..8191
    const int c = t >> 3;          // code
    const int g = t & 7;           // granule (8 floats)
    if (t < KK) hist[t] = 0u;
    const float* ep = emb + (size_t)c * VV + g * 8;
    float4 f0 = *(const float4*)(ep);
    float4 f1 = *(const float4*)(ep + 4);
    float s = 0.f;
    s=fmaf(f0.x,f0.x,s); s=fmaf(f0.y,f0.y,s); s=fmaf(f0.z,f0.z,s); s=fmaf(f0.w,f0.w,s);
    s=fmaf(f1.x,f1.x,s); s=fmaf(f1.y,f1.y,s); s=fmaf(f1.z,f1.z,s); s=fmaf(f1.w,f1.w,s);
    union { short sh[8]; bf16x8 v; } pk;
    pk.sh[0]=f2bf(f0.x); pk.sh[1]=f2bf(f0.y); pk.sh[2]=f2bf(f0.z); pk.sh[3]=f2bf(f0.w);
    pk.sh[4]=f2bf(f1.x); pk.sh[5]=f2bf(f1.y); pk.sh[6]=f2bf(f1.z); pk.sh[7]=f2bf(f1.w);
    const int T = c >> 4, cc = c & 15;
    short* dst = cb + (size_t)T * 1024 + (g >> 2) * 512 + ((g & 3) * 16 + cc) * 8;
    *(bf16x8*)dst = pk.v;
    s += __shfl_xor(s, 1, 64);
    s += __shfl_xor(s, 2, 64);
    s += __shfl_xor(s, 4, 64);
    if (g == 0) cinit[c] = 1.0f - 0.5f * s;   // MFMA C-init; scores in (0.85,1.15)
}

// ===== FULL kernel: byte-identical structure to r8 (92.4us baseline) =====
__global__ __launch_bounds__(512, 4) void vq_main(
    const float* __restrict__ x, const float* __restrict__ emb,
    const float* __restrict__ cinit, const short* __restrict__ cb,
    unsigned int* __restrict__ hist,
    float* __restrict__ out0, float* __restrict__ out1, float* __restrict__ out2)
{
    __shared__ __align__(16) char  sA[SPB * 128];
    __shared__ float    sXn[SPB];
    __shared__ unsigned sRed[SPB][NW + 1];
    __shared__ unsigned sPkF[SPB];

    const int tid  = threadIdx.x;
    const int lane = tid & 63;
    const int wv   = tid >> 6;
    const int col  = lane & 15;
    const int quad = lane >> 4;
    const int samp0 = blockIdx.x * SPB;

    {
        const int s = tid >> 3, g = tid & 7;
        const float* xp = x + (size_t)(samp0 + s) * VV + g * 8;
        float4 f0 = *(const float4*)(xp);
        float4 f1 = *(const float4*)(xp + 4);
        float sm = 0.f;
        sm=fmaf(f0.x,f0.x,sm); sm=fmaf(f0.y,f0.y,sm); sm=fmaf(f0.z,f0.z,sm); sm=fmaf(f0.w,f0.w,sm);
        sm=fmaf(f1.x,f1.x,sm); sm=fmaf(f1.y,f1.y,sm); sm=fmaf(f1.z,f1.z,sm); sm=fmaf(f1.w,f1.w,sm);
        union { short sh[8]; bf16x8 v; } pa;
        pa.sh[0]=f2bf(f0.x); pa.sh[1]=f2bf(f0.y); pa.sh[2]=f2bf(f0.z); pa.sh[3]=f2bf(f0.w);
        pa.sh[4]=f2bf(f1.x); pa.sh[5]=f2bf(f1.y); pa.sh[6]=f2bf(f1.z); pa.sh[7]=f2bf(f1.w);
        short* base = (short*)(sA + s * 128);
        *(bf16x8*)(base + ((g ^ (s & 7)) << 3)) = pa.v;
        sm += __shfl_xor(sm, 1, 64);
        sm += __shfl_xor(sm, 2, 64);
        sm += __shfl_xor(sm, 4, 64);
        if ((tid & 7) == 0) sXn[s] = sm;
    }

    const int rb0 = col * 128 + (( quad      ^ (col & 7)) << 4);
    const int rb1 = col * 128 + (((4 + quad) ^ (col & 7)) << 4);

    unsigned pmv[NMT];
    #pragma unroll
    for (int j = 0; j < NMT; ++j) pmv[j] = 0u;

    bf16x8 af0[2][TPW], af1[2][TPW];
    f32x4  cv[2][TPW];
    #pragma unroll
    for (int t = 0; t < TPW; ++t) {
        const char* cp = (const char*)cb + (size_t)(wv * TPW + t) * 2048;
        af0[0][t] = *(const bf16x8*)(cp + lane * 16);
        af1[0][t] = *(const bf16x8*)(cp + 1024 + lane * 16);
        cv[0][t]  = *(const f32x4*)(cinit + (wv * TPW + t) * 16 + quad * 4);
    }
    __syncthreads();

    #pragma unroll
    for (int p = 0; p < NPASS; ++p) {
        const int cur = p & 1, nxt = cur ^ 1;
        if (p + 1 < NPASS) {
            const int Tn = (p + 1) * 16 + wv * TPW;
            #pragma unroll
            for (int t = 0; t < TPW; ++t) {
                const char* cp = (const char*)cb + (size_t)(Tn + t) * 2048;
                af0[nxt][t] = *(const bf16x8*)(cp + lane * 16);
                af1[nxt][t] = *(const bf16x8*)(cp + 1024 + lane * 16);
                cv[nxt][t]  = *(const f32x4*)(cinit + (Tn + t) * 16 + quad * 4);
            }
        }
        const int Tb = p * 16 + wv * TPW;
        #pragma unroll
        for (int mt = 0; mt < NMT; ++mt) {
            const char* Bp = sA + mt * 2048;
            bf16x8 b0 = *(const bf16x8*)(Bp + rb0);
            bf16x8 b1 = *(const bf16x8*)(Bp + rb1);
            #pragma unroll
            for (int t = 0; t < TPW; ++t) {
                f32x4 acc = __builtin_amdgcn_mfma_f32_16x16x32_bf16(af0[cur][t], b0, cv[cur][t], 0, 0, 0);
                acc       = __builtin_amdgcn_mfma_f32_16x16x32_bf16(af1[cur][t], b1, acc,        0, 0, 0);
                const unsigned tg = 1023u - (unsigned)((Tb + t) * 16 + quad * 4);
                unsigned u0 = ((__float_as_uint(acc[0]) & 0xFFFFFC00u) | tg);
                unsigned u1 = ((__float_as_uint(acc[1]) & 0xFFFFFC00u) | tg) - 1u;
                unsigned u2 = ((__float_as_uint(acc[2]) & 0xFFFFFC00u) | tg) - 2u;
                unsigned u3 = ((__float_as_uint(acc[3]) & 0xFFFFFC00u) | tg) - 3u;
                unsigned m0 = u0 > u1 ? u0 : u1;
                unsigned m1 = u2 > u3 ? u2 : u3;
                unsigned mm = m0 > m1 ? m0 : m1;
                pmv[mt] = pmv[mt] > mm ? pmv[mt] : mm;
            }
        }
    }

    #pragma unroll
    for (int j = 0; j < NMT; ++j) {
        unsigned o;
        o = (unsigned)__shfl_xor((int)pmv[j], 16, 64); pmv[j] = o > pmv[j] ? o : pmv[j];
        o = (unsigned)__shfl_xor((int)pmv[j], 32, 64); pmv[j] = o > pmv[j] ? o : pmv[j];
    }
    {
        unsigned w0 = (quad & 1) ? pmv[1] : pmv[0];
        unsigned w1 = (quad & 1) ? pmv[3] : pmv[2];
        unsigned lo = (quad & 2) ? w1 : w0;
        sRed[quad * 16 + col][wv] = lo;
    }
    __syncthreads();

    if (tid < SPB) {
        unsigned pbest = sRed[tid][0];
        #pragma unroll
        for (int w = 1; w < NW; ++w) {
            unsigned o = sRed[tid][w];
            pbest = o > pbest ? o : pbest;
        }
        sPkF[tid] = pbest;
        int   code = 1023 - (int)(pbest & 1023u);
        float sf   = __uint_as_float(pbest & 0xFFFFFC00u);
        float d    = fmaf(-2.f, sf - 1.0f, sXn[tid]);
        int n = samp0 + tid;
        out1[n] = d;
        out2[n] = d;
        atomicAdd(&hist[code], 1u);
    }
    __syncthreads();

    {
        float4* dstB = (float4*)(out0 + (size_t)samp0 * VV);
        #pragma unroll
        for (int i = 0; i < 2; ++i) {
            const int idx  = i * 512 + tid;
            const int smp  = idx >> 4;
            const int part = idx & 15;
            const int code = 1023 - (int)(sPkF[smp] & 1023u);
            dstB[idx] = *((const float4*)(emb + (size_t)code * VV) + part);
        }
    }
}

// ===== PROBE: staging + frag stream + MFMA/VALU loop ONLY; epilogue replaced by
// a per-thread sink store into ws scratch (keeps all compute live, rule #17).
// Touches no outputs and no hist -> results identical to vq_main alone.
__global__ __launch_bounds__(512, 4) void vq_probe(
    const float* __restrict__ x, const float* __restrict__ cinit,
    const short* __restrict__ cb, unsigned int* __restrict__ sink)
{
    __shared__ __align__(16) char  sA[SPB * 128];
    __shared__ float    sXn[SPB];

    const int tid  = threadIdx.x;
    const int lane = tid & 63;
    const int wv   = tid >> 6;
    const int col  = lane & 15;
    const int quad = lane >> 4;
    const int samp0 = blockIdx.x * SPB;

    {
        const int s = tid >> 3, g = tid & 7;
        const float* xp = x + (size_t)(samp0 + s) * VV + g * 8;
        float4 f0 = *(const float4*)(xp);
        float4 f1 = *(const float4*)(xp + 4);
        float sm = 0.f;
        sm=fmaf(f0.x,f0.x,sm); sm=fmaf(f0.y,f0.y,sm); sm=fmaf(f0.z,f0.z,sm); sm=fmaf(f0.w,f0.w,sm);
        sm=fmaf(f1.x,f1.x,sm); sm=fmaf(f1.y,f1.y,sm); sm=fmaf(f1.z,f1.z,sm); sm=fmaf(f1.w,f1.w,sm);
        union { short sh[8]; bf16x8 v; } pa;
        pa.sh[0]=f2bf(f0.x); pa.sh[1]=f2bf(f0.y); pa.sh[2]=f2bf(f0.z); pa.sh[3]=f2bf(f0.w);
        pa.sh[4]=f2bf(f1.x); pa.sh[5]=f2bf(f1.y); pa.sh[6]=f2bf(f1.z); pa.sh[7]=f2bf(f1.w);
        short* base = (short*)(sA + s * 128);
        *(bf16x8*)(base + ((g ^ (s & 7)) << 3)) = pa.v;
        sm += __shfl_xor(sm, 1, 64);
        sm += __shfl_xor(sm, 2, 64);
        sm += __shfl_xor(sm, 4, 64);
        if ((tid & 7) == 0) sXn[s] = sm;
    }

    const int rb0 = col * 128 + (( quad      ^ (col & 7)) << 4);
    const int rb1 = col * 128 + (((4 + quad) ^ (col & 7)) << 4);

    unsigned pmv[NMT];
    #pragma unroll
    for (int j = 0; j < NMT; ++j) pmv[j] = 0u;

    bf16x8 af0[2][TPW], af1[2][TPW];
    f32x4  cv[2][TPW];
    #pragma unroll
    for (int t = 0; t < TPW; ++t) {
        const char* cp = (const char*)cb + (size_t)(wv * TPW + t) * 2048;
        af0[0][t] = *(const bf16x8*)(cp + lane * 16);
        af1[0][t] = *(const bf16x8*)(cp + 1024 + lane * 16);
        cv[0][t]  = *(const f32x4*)(cinit + (wv * TPW + t) * 16 + quad * 4);
    }
    __syncthreads();

    #pragma unroll
    for (int p = 0; p < NPASS; ++p) {
        const int cur = p & 1, nxt = cur ^ 1;
        if (p + 1 < NPASS) {
            const int Tn = (p + 1) * 16 + wv * TPW;
            #pragma unroll
            for (int t = 0; t < TPW; ++t) {
                const char* cp = (const char*)cb + (size_t)(Tn + t) * 2048;
                af0[nxt][t] = *(const bf16x8*)(cp + lane * 16);
                af1[nxt][t] = *(const bf16x8*)(cp + 1024 + lane * 16);
                cv[nxt][t]  = *(const f32x4*)(cinit + (Tn + t) * 16 + quad * 4);
            }
        }
        const int Tb = p * 16 + wv * TPW;
        #pragma unroll
        for (int mt = 0; mt < NMT; ++mt) {
            const char* Bp = sA + mt * 2048;
            bf16x8 b0 = *(const bf16x8*)(Bp + rb0);
            bf16x8 b1 = *(const bf16x8*)(Bp + rb1);
            #pragma unroll
            for (int t = 0; t < TPW; ++t) {
                f32x4 acc = __builtin_amdgcn_mfma_f32_16x16x32_bf16(af0[cur][t], b0, cv[cur][t], 0, 0, 0);
                acc       = __builtin_amdgcn_mfma_f32_16x16x32_bf16(af1[cur][t], b1, acc,        0, 0, 0);
                const unsigned tg = 1023u - (unsigned)((Tb + t) * 16 + quad * 4);
                unsigned u0 = ((__float_as_uint(acc[0]) & 0xFFFFFC00u) | tg);
                unsigned u1 = ((__float_as_uint(acc[1]) & 0xFFFFFC00u) | tg) - 1u;
                unsigned u2 = ((__float_as_uint(acc[2]) & 0xFFFFFC00u) | tg) - 2u;
                unsigned u3 = ((__float_as_uint(acc[3]) & 0xFFFFFC00u) | tg) - 3u;
                unsigned m0 = u0 > u1 ? u0 : u1;
                unsigned m1 = u2 > u3 ? u2 : u3;
                unsigned mm = m0 > m1 ? m0 : m1;
                pmv[mt] = pmv[mt] > mm ? pmv[mt] : mm;
            }
        }
    }

    // sink: every pmv stays live; one plain store per thread into ws scratch
    sink[(size_t)blockIdx.x * 512 + tid] = pmv[0] ^ pmv[1] ^ pmv[2] ^ pmv[3] ^ sXn[0] != 0.f;
}

// entropy: separate 1-block kernel (plain loads; kernel-boundary coherence).
__global__ void vq_ent(const unsigned int* __restrict__ hist, float* __restrict__ entOut) {
    __shared__ float sPart[16];
    const int tid  = threadIdx.x;
    const int lane = tid & 63;
    const int wv   = tid >> 6;
    unsigned c = hist[tid];
    float e = 0.f;
    if (c) { float pr = (float)c * (1.0f / (float)NS); e = -pr * logf(pr); }
    #pragma unroll
    for (int off = 32; off > 0; off >>= 1) e += __shfl_down(e, off, 64);
    if (lane == 0) sPart[wv] = e;
    __syncthreads();
    if (tid == 0) {
        float s = 0.f;
        #pragma unroll
        for (int i = 0; i < 16; ++i) s += sPart[i];
        entOut[0] = s;
    }
}

extern "C" void kernel_launch(void* const* d_in, const int* in_sizes, int n_in,
                              void* d_out, int out_size, void* d_ws, size_t ws_size,
                              hipStream_t stream) {
    const float* x   = (const float*)d_in[0];   // (8,8192,1,64) fp32
    const float* emb = (const float*)d_in[1];   // (1,1024,64) fp32
    float* out = (float*)d_out;
    unsigned int* hist  = (unsigned int*)d_ws;
    float*        cinit = (float*)((char*)d_ws + 4096);
    short*        cb    = (short*)((char*)d_ws + 8192);     // frag-linear bf16 codebook
    unsigned int* sink  = (unsigned int*)((char*)d_ws + (1 << 20));   // probe scratch

    vq_prep<<<32, 256, 0, stream>>>(emb, hist, cinit, cb);
    vq_main<<<NB, 512, 0, stream>>>(x, emb, cinit, cb, hist,
                                    out + OUT0_OFF, out + OUT1_OFF, out + OUT2_OFF);
    // --- diagnostic probes (after main: warm caches, ramped clock) ---
    vq_probe<<<NB, 512, 0, stream>>>(x, cinit, cb, sink);
    vq_probe<<<NB, 512, 0, stream>>>(x, cinit, cb, sink);
    vq_ent<<<1, 1024, 0, stream>>>(hist, out + ENT_OFF);
}

// Round 11
// 93.006 us; speedup vs baseline: 1.9119x; 1.9119x over previous
//
#include <hip/hip_runtime.h>
#include <math.h>

// Problem constants: N=8, S=8192, C=1, K=1024, V=64
#define NS   65536
#define KK   1024
#define VV   64
#define SPB  64               // samples per block (4 m-tiles of 16)
#define NB   (NS / SPB)       // 1024 blocks
#define NW   8                // waves per block (512 threads)
#define TPW  2                // code tiles per wave per pass (32 codes)
#define NPASS 4               // 8 waves x 2 tiles x 4 passes = 64 tiles = 1024 codes
#define NMT  (SPB / 16)       // 4 sample-tiles per block

// Output layout (flat, return order):
#define OUT0_OFF 0            // (8,8192,1,64) = 4,194,304
#define OUT1_OFF 4194304
#define OUT2_OFF 4259840
#define ENT_OFF  4325376      // entropy scalar

// ws layout: [0,4K) hist u32; [4K,8K) cinit f32; [8K,136K) frag-linear bf16 codebook

typedef __attribute__((ext_vector_type(8))) short bf16x8;
typedef __attribute__((ext_vector_type(4))) float f32x4;

__device__ __forceinline__ short f2bf(float f) {
    unsigned u = __float_as_uint(f);
    u = (u + 0x7fffu + ((u >> 16) & 1u)) >> 16;   // RNE
    return (short)u;
}

// prep (wide): 8192 threads, one (code, granule) each. FRAG-LINEAR bf16 codebook.
__global__ void vq_prep(const float* __restrict__ emb, unsigned int* __restrict__ hist,
                        float* __restrict__ cinit, short* __restrict__ cb) {
    const int t = blockIdx.x * blockDim.x + threadIdx.x;   // 0..8191
    const int c = t >> 3;          // code
    const int g = t & 7;           // granule (8 floats)
    if (t < KK) hist[t] = 0u;
    const float* ep = emb + (size_t)c * VV + g * 8;
    float4 f0 = *(const float4*)(ep);
    float4 f1 = *(const float4*)(ep + 4);
    float s = 0.f;
    s=fmaf(f0.x,f0.x,s); s=fmaf(f0.y,f0.y,s); s=fmaf(f0.z,f0.z,s); s=fmaf(f0.w,f0.w,s);
    s=fmaf(f1.x,f1.x,s); s=fmaf(f1.y,f1.y,s); s=fmaf(f1.z,f1.z,s); s=fmaf(f1.w,f1.w,s);
    union { short sh[8]; bf16x8 v; } pk;
    pk.sh[0]=f2bf(f0.x); pk.sh[1]=f2bf(f0.y); pk.sh[2]=f2bf(f0.z); pk.sh[3]=f2bf(f0.w);
    pk.sh[4]=f2bf(f1.x); pk.sh[5]=f2bf(f1.y); pk.sh[6]=f2bf(f1.z); pk.sh[7]=f2bf(f1.w);
    const int T = c >> 4, cc = c & 15;
    short* dst = cb + (size_t)T * 1024 + (g >> 2) * 512 + ((g & 3) * 16 + cc) * 8;
    *(bf16x8*)dst = pk.v;
    s += __shfl_xor(s, 1, 64);
    s += __shfl_xor(s, 2, 64);
    s += __shfl_xor(s, 4, 64);
    if (g == 0) cinit[c] = 1.0f - 0.5f * s;   // MFMA C-init; scores in (0.85,1.15)
}

// r11: r8 structure + cheap pack: per-result tag is a HOISTED OR-constant
// (tg_r = tg - r, computed once per (p,t)) -> one v_and_or_b32 per result,
// and a max3-fusable reduction tree. ~160 VALU ops/wave removed from the loop.
__global__ __launch_bounds__(512, 4) void vq_main(
    const float* __restrict__ x, const float* __restrict__ emb,
    const float* __restrict__ cinit, const short* __restrict__ cb,
    unsigned int* __restrict__ hist,
    float* __restrict__ out0, float* __restrict__ out1, float* __restrict__ out2)
{
    __shared__ __align__(16) char  sA[SPB * 128];
    __shared__ float    sXn[SPB];
    __shared__ unsigned sRed[SPB][NW + 1];
    __shared__ unsigned sPkF[SPB];

    const int tid  = threadIdx.x;
    const int lane = tid & 63;
    const int wv   = tid >> 6;
    const int col  = lane & 15;
    const int quad = lane >> 4;
    const int samp0 = blockIdx.x * SPB;

    {
        const int s = tid >> 3, g = tid & 7;
        const float* xp = x + (size_t)(samp0 + s) * VV + g * 8;
        float4 f0 = *(const float4*)(xp);
        float4 f1 = *(const float4*)(xp + 4);
        float sm = 0.f;
        sm=fmaf(f0.x,f0.x,sm); sm=fmaf(f0.y,f0.y,sm); sm=fmaf(f0.z,f0.z,sm); sm=fmaf(f0.w,f0.w,sm);
        sm=fmaf(f1.x,f1.x,sm); sm=fmaf(f1.y,f1.y,sm); sm=fmaf(f1.z,f1.z,sm); sm=fmaf(f1.w,f1.w,sm);
        union { short sh[8]; bf16x8 v; } pa;
        pa.sh[0]=f2bf(f0.x); pa.sh[1]=f2bf(f0.y); pa.sh[2]=f2bf(f0.z); pa.sh[3]=f2bf(f0.w);
        pa.sh[4]=f2bf(f1.x); pa.sh[5]=f2bf(f1.y); pa.sh[6]=f2bf(f1.z); pa.sh[7]=f2bf(f1.w);
        short* base = (short*)(sA + s * 128);
        *(bf16x8*)(base + ((g ^ (s & 7)) << 3)) = pa.v;
        sm += __shfl_xor(sm, 1, 64);
        sm += __shfl_xor(sm, 2, 64);
        sm += __shfl_xor(sm, 4, 64);
        if ((tid & 7) == 0) sXn[s] = sm;
    }

    const int rb0 = col * 128 + (( quad      ^ (col & 7)) << 4);
    const int rb1 = col * 128 + (((4 + quad) ^ (col & 7)) << 4);

    unsigned pmv[NMT];
    #pragma unroll
    for (int j = 0; j < NMT; ++j) pmv[j] = 0u;

    bf16x8 af0[2][TPW], af1[2][TPW];
    f32x4  cv[2][TPW];
    #pragma unroll
    for (int t = 0; t < TPW; ++t) {
        const char* cp = (const char*)cb + (size_t)(wv * TPW + t) * 2048;
        af0[0][t] = *(const bf16x8*)(cp + lane * 16);
        af1[0][t] = *(const bf16x8*)(cp + 1024 + lane * 16);
        cv[0][t]  = *(const f32x4*)(cinit + (wv * TPW + t) * 16 + quad * 4);
    }
    __syncthreads();

    #pragma unroll
    for (int p = 0; p < NPASS; ++p) {
        const int cur = p & 1, nxt = cur ^ 1;
        if (p + 1 < NPASS) {
            const int Tn = (p + 1) * 16 + wv * TPW;
            #pragma unroll
            for (int t = 0; t < TPW; ++t) {
                const char* cp = (const char*)cb + (size_t)(Tn + t) * 2048;
                af0[nxt][t] = *(const bf16x8*)(cp + lane * 16);
                af1[nxt][t] = *(const bf16x8*)(cp + 1024 + lane * 16);
                cv[nxt][t]  = *(const f32x4*)(cinit + (Tn + t) * 16 + quad * 4);
            }
        }
        const int Tb = p * 16 + wv * TPW;
        // hoisted per-(p,t) tag constants: tg_r = 1023 - code(T,quad,r).
        // code_base = (Tb+t)*16 + quad*4 (mult of 4) -> tg low 2 bits = 3 >= r,
        // so OR with the 22-bit-masked score == the old ((bits|tg)-r) packing.
        unsigned tgc[TPW][4];
        #pragma unroll
        for (int t = 0; t < TPW; ++t) {
            const unsigned tg = 1023u - (unsigned)((Tb + t) * 16 + quad * 4);
            tgc[t][0] = tg; tgc[t][1] = tg - 1u; tgc[t][2] = tg - 2u; tgc[t][3] = tg - 3u;
        }
        #pragma unroll
        for (int mt = 0; mt < NMT; ++mt) {
            const char* Bp = sA + mt * 2048;
            bf16x8 b0 = *(const bf16x8*)(Bp + rb0);
            bf16x8 b1 = *(const bf16x8*)(Bp + rb1);
            #pragma unroll
            for (int t = 0; t < TPW; ++t) {
                f32x4 acc = __builtin_amdgcn_mfma_f32_16x16x32_bf16(af0[cur][t], b0, cv[cur][t], 0, 0, 0);
                acc       = __builtin_amdgcn_mfma_f32_16x16x32_bf16(af1[cur][t], b1, acc,        0, 0, 0);
                // one v_and_or_b32 per result, then a max3-fusable tree:
                unsigned u0 = (__float_as_uint(acc[0]) & 0xFFFFFC00u) | tgc[t][0];
                unsigned u1 = (__float_as_uint(acc[1]) & 0xFFFFFC00u) | tgc[t][1];
                unsigned u2 = (__float_as_uint(acc[2]) & 0xFFFFFC00u) | tgc[t][2];
                unsigned u3 = (__float_as_uint(acc[3]) & 0xFFFFFC00u) | tgc[t][3];
                unsigned i0 = u2 > u3 ? u2 : u3;
                unsigned i1 = i0 > pmv[mt] ? i0 : pmv[mt];      // max3(u2,u3,pmv)
                unsigned i2 = u0 > u1 ? u0 : u1;
                pmv[mt] = i2 > i1 ? i2 : i1;                    // max3(u0,u1,i1)
            }
        }
    }

    #pragma unroll
    for (int j = 0; j < NMT; ++j) {
        unsigned o;
        o = (unsigned)__shfl_xor((int)pmv[j], 16, 64); pmv[j] = o > pmv[j] ? o : pmv[j];
        o = (unsigned)__shfl_xor((int)pmv[j], 32, 64); pmv[j] = o > pmv[j] ? o : pmv[j];
    }
    {
        unsigned w0 = (quad & 1) ? pmv[1] : pmv[0];
        unsigned w1 = (quad & 1) ? pmv[3] : pmv[2];
        unsigned lo = (quad & 2) ? w1 : w0;            // pmv[quad]
        sRed[quad * 16 + col][wv] = lo;
    }
    __syncthreads();

    if (tid < SPB) {
        unsigned pbest = sRed[tid][0];
        #pragma unroll
        for (int w = 1; w < NW; ++w) {
            unsigned o = sRed[tid][w];
            pbest = o > pbest ? o : pbest;
        }
        sPkF[tid] = pbest;
        int   code = 1023 - (int)(pbest & 1023u);
        float sf   = __uint_as_float(pbest & 0xFFFFFC00u);
        float d    = fmaf(-2.f, sf - 1.0f, sXn[tid]);   // sf-1 exact (Sterbenz)
        int n = samp0 + tid;
        out1[n] = d;
        out2[n] = d;
        atomicAdd(&hist[code], 1u);   // device-scope; visible to vq_ent via kernel boundary
    }
    __syncthreads();

    {
        float4* dstB = (float4*)(out0 + (size_t)samp0 * VV);
        #pragma unroll
        for (int i = 0; i < 2; ++i) {
            const int idx  = i * 512 + tid;
            const int smp  = idx >> 4;
            const int part = idx & 15;
            const int code = 1023 - (int)(sPkF[smp] & 1023u);
            dstB[idx] = *((const float4*)(emb + (size_t)code * VV) + part);
        }
    }
}

// entropy: separate 1-block kernel (plain loads; kernel-boundary coherence).
__global__ void vq_ent(const unsigned int* __restrict__ hist, float* __restrict__ entOut) {
    __shared__ float sPart[16];
    const int tid  = threadIdx.x;
    const int lane = tid & 63;
    const int wv   = tid >> 6;
    unsigned c = hist[tid];
    float e = 0.f;
    if (c) { float pr = (float)c * (1.0f / (float)NS); e = -pr * logf(pr); }
    #pragma unroll
    for (int off = 32; off > 0; off >>= 1) e += __shfl_down(e, off, 64);
    if (lane == 0) sPart[wv] = e;
    __syncthreads();
    if (tid == 0) {
        float s = 0.f;
        #pragma unroll
        for (int i = 0; i < 16; ++i) s += sPart[i];
        entOut[0] = s;
    }
}

extern "C" void kernel_launch(void* const* d_in, const int* in_sizes, int n_in,
                              void* d_out, int out_size, void* d_ws, size_t ws_size,
                              hipStream_t stream) {
    const float* x   = (const float*)d_in[0];   // (8,8192,1,64) fp32
    const float* emb = (const float*)d_in[1];   // (1,1024,64) fp32
    float* out = (float*)d_out;
    unsigned int* hist  = (unsigned int*)d_ws;
    float*        cinit = (float*)((char*)d_ws + 4096);
    short*        cb    = (short*)((char*)d_ws + 8192);   // frag-linear bf16 codebook

    vq_prep<<<32, 256, 0, stream>>>(emb, hist, cinit, cb);
    vq_main<<<NB, 512, 0, stream>>>(x, emb, cinit, cb, hist,
                                    out + OUT0_OFF, out + OUT1_OFF, out + OUT2_OFF);
    vq_ent<<<1, 1024, 0, stream>>>(hist, out + ENT_OFF);
}